// Round 1
// 216.108 us; speedup vs baseline: 1.0507x; 1.0507x over previous
//
#include <hip/hip_runtime.h>

typedef __attribute__((ext_vector_type(4))) float    f32x4;
typedef __attribute__((ext_vector_type(4))) short    s16x4;
typedef __attribute__((ext_vector_type(8))) short    s16x8;
typedef __attribute__((ext_vector_type(8))) _Float16 h16x8;

#define ROWS 16
#define XS_STRIDE 520   // 512 + 8 bf16 pad

__device__ __forceinline__ short f2bf(float f) {
  unsigned u = __float_as_uint(f);
  u = (u + 0x7fffu + ((u >> 16) & 1u)) >> 16;   // RNE
  return (short)u;
}

// ---------------- precompute ----------------
// wF[d2][vt][kt][lane][j] = lin_w[d2][k][v] / sqrt(128), bf16
//   v = vt*16 + (lane&15), k = kt*32 + (lane>>4)*8 + j
// cc[v][ab][j]: j<16 -> C3u[c=j>>2][i=j&3], j in 16..19 -> C2u[i=j-16]  (fp16)
// cu1[v][a*4+i] (f32)
__global__ void precompute_kernel(const float* __restrict__ lin_w,
                                  const float* __restrict__ w1,
                                  const float* __restrict__ w2,
                                  const float* __restrict__ w3,
                                  const float* __restrict__ C1,
                                  const float* __restrict__ C2,
                                  const float* __restrict__ C3,
                                  short*    __restrict__ wF,
                                  _Float16* __restrict__ cc,
                                  float*    __restrict__ cu1) {
  int tid = blockIdx.x * blockDim.x + threadIdx.x;
  int nth = gridDim.x * blockDim.x;
  const float rs = 0.088388347648318447f;  // 1/sqrt(128)
  // weight fragments, coalesced per-wave layout, rs folded in
  for (int idx = tid; idx < 6 * 8 * 4 * 64 * 8; idx += nth) {
    int j  = idx & 7;
    int ln = (idx >> 3) & 63;
    int kt = (idx >> 9) & 3;
    int vt = (idx >> 11) & 7;
    int d2 = idx >> 14;
    int v  = vt * 16 + (ln & 15);
    int k  = kt * 32 + (ln >> 4) * 8 + j;
    wF[idx] = f2bf(lin_w[(d2 * 128 + k) * 128 + v] * rs);
  }
  // fused C2u/C3u table (fp16)
  for (int idx = tid; idx < 128 * 16 * 20; idx += nth) {
    int v  = idx / 320;
    int r  = idx - v * 320;
    int ab = r / 20;
    int j  = r - ab * 20;
    int a = ab >> 2, b = ab & 3;
    float s = 0.f;
    if (j < 16) {
      int c = j >> 2, i = j & 3;
      const float* p = C3 + (((a * 4 + b) * 4 + c) * 4 + i) * 12;
      #pragma unroll
      for (int w = 0; w < 12; ++w) s += p[w] * w3[w * 128 + v];
    } else {
      int i = j - 16;
      const float* p = C2 + ((a * 4 + b) * 4 + i) * 5;
      #pragma unroll
      for (int w = 0; w < 5; ++w) s += p[w] * w2[w * 128 + v];
    }
    cc[(v * 16 + ab) * 24 + j] = (_Float16)s;
  }
  // cu1[v][a*4+i]
  for (int idx = tid; idx < 128 * 16; idx += nth) {
    int v = idx >> 4;
    int ai = idx & 15;
    int a = ai >> 2, i = ai & 3;
    cu1[idx] = C1[(a * 4 + i) * 2 + 0] * w1[v] + C1[(a * 4 + i) * 2 + 1] * w1[128 + v];
  }
}

// ---------------- fused main: MFMA linear (y in regs) + fp32 contraction ----------------
// 512 threads = 8 waves; wave w owns vt = w (v = w*16 + vl). One 16-row tile per block.
__launch_bounds__(512, 4)
__global__ void main_kernel(const float* __restrict__ x,
                            const short* __restrict__ wF,
                            const _Float16* __restrict__ cc,
                            const float* __restrict__ cu1,
                            float* __restrict__ out) {
  __shared__ short xs[ROWS * XS_STRIDE];   // [row][a*128+k], bf16

  const int t    = threadIdx.x;
  const int lane = t & 63;
  const int wave = t >> 6;      // 0..7 == vt
  const int vl   = lane & 15;
  const int quad = lane >> 4;   // 0..3
  const int n0   = blockIdx.x * ROWS;

  // stage x tile -> bf16 LDS (coalesced float4 loads)
  const float4* xsrc = (const float4*)(x + (size_t)n0 * 512);
  #pragma unroll
  for (int i2 = 0; i2 < 4; ++i2) {
    int f = i2 * 512 + t;          // float4 id, 0..2047
    float4 xv = xsrc[f];
    int row = f >> 7, c4 = f & 127;
    s16x4 pk;
    pk[0] = f2bf(xv.x); pk[1] = f2bf(xv.y); pk[2] = f2bf(xv.z); pk[3] = f2bf(xv.w);
    *(s16x4*)&xs[row * XS_STRIDE + c4 * 4] = pk;
  }
  __syncthreads();

  // y[da][r]: da = d*4+a; this wave's v = wave*16+vl; row = quad*4+r
  float yreg[12][4];

  #pragma unroll
  for (int d2 = 0; d2 < 6; ++d2) {
    // B fragments for this wave: coalesced 16B/lane loads from L2 (rs pre-folded)
    s16x8 bf[4];
    {
      const s16x8* wsrc = (const s16x8*)wF + (d2 * 8 + wave) * 4 * 64 + lane;
      #pragma unroll
      for (int kt = 0; kt < 4; ++kt) bf[kt] = wsrc[kt * 64];
    }
    const int d = d2 >> 1, blk = d2 & 1;
    const int a_begin = blk ? 1 : 0;
    const int a_end   = blk ? 4 : 1;
    #pragma unroll
    for (int a = a_begin; a < a_end; ++a) {
      f32x4 acc = {0.f, 0.f, 0.f, 0.f};
      #pragma unroll
      for (int kt = 0; kt < 4; ++kt) {
        s16x8 af = *(const s16x8*)&xs[vl * XS_STRIDE + a * 128 + kt * 32 + quad * 8];
        acc = __builtin_amdgcn_mfma_f32_16x16x32_bf16(af, bf[kt], acc, 0, 0, 0);
      }
      const int da = d * 4 + a;
      #pragma unroll
      for (int r = 0; r < 4; ++r) yreg[da][r] = acc[r];
    }
  }

  // ---------------- contraction (fp32, y in regs, coeffs streamed from L2) ----------------
  const int v = wave * 16 + vl;
  float acc[4][4];   // [i][r]

  // degree 1
  {
    const f32x4* cu1v = (const f32x4*)(cu1 + v * 16);
    float c1[16];
    #pragma unroll
    for (int q = 0; q < 4; ++q) {
      f32x4 tv = cu1v[q];
      c1[4 * q + 0] = tv[0]; c1[4 * q + 1] = tv[1]; c1[4 * q + 2] = tv[2]; c1[4 * q + 3] = tv[3];
    }
    #pragma unroll
    for (int i = 0; i < 4; ++i)
      #pragma unroll
      for (int r = 0; r < 4; ++r) {
        float s = c1[0 * 4 + i] * yreg[0][r];
        s = fmaf(c1[1 * 4 + i], yreg[1][r], s);
        s = fmaf(c1[2 * 4 + i], yreg[2][r], s);
        s = fmaf(c1[3 * 4 + i], yreg[3][r], s);
        acc[i][r] = s;
      }
  }

  // degrees 2+3: out[i] += G[ab] * (C2u[ab,i] + sum_c C3u[ab,c,i]*y3[c])
  const _Float16* ccv = cc + v * (16 * 24);
  #pragma unroll
  for (int ab = 0; ab < 16; ++ab) {
    const int a = ab >> 2, b = ab & 3;
    const _Float16* p = ccv + ab * 24;
    h16x8 h0 = *(const h16x8*)p;
    h16x8 h1 = *(const h16x8*)(p + 8);
    h16x8 h2 = *(const h16x8*)(p + 16);
    float cj[20];
    #pragma unroll
    for (int j = 0; j < 8; ++j) { cj[j] = (float)h0[j]; cj[8 + j] = (float)h1[j]; }
    #pragma unroll
    for (int j = 0; j < 4; ++j) cj[16 + j] = (float)h2[j];
    #pragma unroll
    for (int r = 0; r < 4; ++r) {
      const float G = yreg[a][r] * yreg[4 + b][r];
      #pragma unroll
      for (int i = 0; i < 4; ++i) {
        float s = cj[16 + i];
        s = fmaf(cj[0 + i],  yreg[8][r],  s);
        s = fmaf(cj[4 + i],  yreg[9][r],  s);
        s = fmaf(cj[8 + i],  yreg[10][r], s);
        s = fmaf(cj[12 + i], yreg[11][r], s);
        acc[i][r] = fmaf(G, s, acc[i][r]);
      }
    }
  }

  // store
  #pragma unroll
  for (int r = 0; r < 4; ++r) {
    const int n = n0 + quad * 4 + r;
    #pragma unroll
    for (int i = 0; i < 4; ++i) out[(size_t)n * 512 + i * 128 + v] = acc[i][r];
  }
}

extern "C" void kernel_launch(void* const* d_in, const int* in_sizes, int n_in,
                              void* d_out, int out_size, void* d_ws, size_t ws_size,
                              hipStream_t stream) {
  const float* x     = (const float*)d_in[0];
  const float* lin_w = (const float*)d_in[1];
  const float* w1    = (const float*)d_in[2];
  const float* w2    = (const float*)d_in[3];
  const float* w3    = (const float*)d_in[4];
  const float* C1    = (const float*)d_in[5];
  const float* C2    = (const float*)d_in[6];
  const float* C3    = (const float*)d_in[7];

  char* ws = (char*)d_ws;
  short*    wF  = (short*)ws;                     // 196608 B
  _Float16* cc  = (_Float16*)(ws + 196608);       //  98304 B
  float*    cu1 = (float*)(ws + 294912);          //   8192 B
  float*    out = (float*)d_out;

  hipLaunchKernelGGL(precompute_kernel, dim3(384), dim3(256), 0, stream,
                     lin_w, w1, w2, w3, C1, C2, C3, wF, cc, cu1);
  hipLaunchKernelGGL(main_kernel, dim3(2048), dim3(512), 0, stream,
                     x, wF, cc, cu1, out);
}